// Round 10
// baseline (110.230 us; speedup 1.0000x reference)
//
#include <hip/hip_runtime.h>

typedef float f32x4 __attribute__((ext_vector_type(4)));
typedef __bf16 bf16x8 __attribute__((ext_vector_type(8)));
typedef unsigned int u32;
typedef unsigned short u16;

#define MTOT 65536
#define BTOT 1024
#define DD 64
#define LOG2E 1.44269504088896340736f
#define MFMA __builtin_amdgcn_mfma_f32_16x16x32_bf16

#define NROWBLK ((MTOT + BTOT) * 24 / 256)   // 6240
#define NVTBLK  (MTOT / 64)                  // 1024

__device__ __forceinline__ u16 f2bf(float f) { return __builtin_bit_cast(u16, (__bf16)f); }
__device__ __forceinline__ u32 pk2(float a, float b) {
    return (u32)f2bf(a) | ((u32)f2bf(b) << 16);
}
__device__ __forceinline__ bf16x8 ldg8(const u16* p) { return *reinterpret_cast<const bf16x8*>(p); }
__device__ __forceinline__ void glds16(const void* g, void* l) {
    __builtin_amdgcn_global_load_lds((const __attribute__((address_space(1))) u32*)g,
                                     (__attribute__((address_space(3))) u32*)l, 16, 0, 0);
}

// ---------------- fused precompute: Qc/KC rows + interleaved Vt ----------------
__global__ __launch_bounds__(256)
void prep_all(const float* __restrict__ q, const float* __restrict__ ctx,
              const float* __restrict__ K, const float* __restrict__ CT,
              const float* __restrict__ TS, const int* __restrict__ mask,
              const float* __restrict__ V,
              u16* __restrict__ Qc, u16* __restrict__ KC, u16* __restrict__ Vt)
{
    __shared__ u16 L[64][68];
    const int blk = blockIdx.x, t = threadIdx.x;

    if (blk < NROWBLK) {
        const int R = MTOT + BTOT;
        int gid = blk * 256 + t;                   // R*24 total, exact
        float4 v = {0.f, 0.f, 0.f, 0.f};
        u16* dst;
        if (gid < R * 16) {                        // feature cols 0..63
            int row = gid >> 4, qd = gid & 15;
            bool isQ = row >= MTOT;
            int r2 = isQ ? row - MTOT : row;
            v = *reinterpret_cast<const float4*>((isQ ? q : K) + (size_t)r2 * 64 + qd * 4);
            if (isQ) { v.x *= LOG2E; v.y *= LOG2E; v.z *= LOG2E; v.w *= LOG2E; }
            dst = (isQ ? Qc : KC) + (size_t)r2 * 96 + qd * 4;
        } else if (gid < R * 20) {                 // context cols 64..79
            int i = gid - R * 16;
            int row = i >> 2, qd = i & 3;
            bool isQ = row >= MTOT;
            int r2 = isQ ? row - MTOT : row;
            v = *reinterpret_cast<const float4*>((isQ ? ctx : CT) + (size_t)r2 * 16 + qd * 4);
            if (isQ) { const float s = 0.5f * LOG2E; v.x *= s; v.y *= s; v.z *= s; v.w *= s; }
            dst = (isQ ? Qc : KC) + (size_t)r2 * 96 + 64 + qd * 4;
        } else {                                   // bias col 80 + pad 81..95
            int i = gid - R * 20;
            int row = i >> 2, qd = i & 3;
            bool isQ = row >= MTOT;
            int r2 = isQ ? row - MTOT : row;
            if (qd == 0)
                v.x = isQ ? LOG2E
                          : (mask[r2] ? 0.3f * __expf(-0.1f * (1000.0f - TS[r2])) : -100.0f);
            dst = (isQ ? Qc : KC) + (size_t)r2 * 96 + 80 + qd * 4;
        }
        ushort4 o = { f2bf(v.x), f2bf(v.y), f2bf(v.z), f2bf(v.w) };
        *reinterpret_cast<ushort4*>(dst) = o;
        return;
    }

    // ---- Vt part: interleaved transpose ----
    const int m0 = (blk - NROWBLK) * 64;
#pragma unroll
    for (int p = 0; p < 4; ++p) {
        int fi = t + p * 256;              // float4 index 0..1023
        int mi = fi >> 4, di = (fi & 15) << 2;
        float4 v = *reinterpret_cast<const float4*>(V + (size_t)(m0 + mi) * 64 + di);
        ushort4 o = { f2bf(v.x), f2bf(v.y), f2bf(v.z), f2bf(v.w) };
        *reinterpret_cast<ushort4*>(&L[mi][di]) = o;
    }
    __syncthreads();
    const int d = t >> 2, seg = t & 3;
    u32 pk[8];
#pragma unroll
    for (int pr = 0; pr < 8; ++pr) {
        int c0 = seg * 16 + pr * 2;
        int g32 = c0 >> 5;
        int i0 = c0 & 31, i1 = (c0 + 1) & 31;
        int mp0 = g32 * 32 + (i0 >> 1) + (i0 & 1) * 16;   // interleave: pairs (x, 16+x)
        int mp1 = g32 * 32 + (i1 >> 1) + (i1 & 1) * 16;
        pk[pr] = (u32)L[mp0][d] | ((u32)L[mp1][d] << 16);
    }
    uint4 A = {pk[0], pk[1], pk[2], pk[3]}, B4 = {pk[4], pk[5], pk[6], pk[7]};
    u16* dst = Vt + (size_t)d * MTOT + m0 + seg * 16;
    *reinterpret_cast<uint4*>(dst)     = A;
    *reinterpret_cast<uint4*>(dst + 8) = B4;
}

// ---------------- main: KC via LDS double-buffer, V from L2, P via per-wave LDS ----------------
__global__ __launch_bounds__(256, 3)
void epmem_mfma(const u16* __restrict__ Qc, const u16* __restrict__ KCg,
                const u16* __restrict__ Vtg,
                float* __restrict__ pl, float* __restrict__ pacc,
                int mper, int NB)
{
    __shared__ __align__(16) u16 KCs[2][64 * 128];   // 32 KB
    __shared__ __align__(16) u16 Pb[4][32][40];      // 10 KB, 80 B rows (conflict-free)

    const int tid = threadIdx.x;
    const int w = tid >> 6, lane = tid & 63;
    const int l15 = lane & 15, g = lane >> 4;

    const int bid = blockIdx.x;
    const int o = (bid & 7) * (NB >> 3) + (bid >> 3);     // XCD-bijective (NB % 8 == 0)
    const int rt = o & 7, ch = o >> 3;
    const int rbase = rt * 128 + w * 32;

    // Q fragments (2 b-subtiles x 3 k-chunks), LOG2E pre-scaled
    const u16* q0 = Qc + (size_t)(rbase + l15) * 96 + g * 8;
    const bf16x8 qf00 = ldg8(q0), qf01 = ldg8(q0 + 32), qf02 = ldg8(q0 + 64);
    const u16* q1 = q0 + 16 * 96;
    const bf16x8 qf10 = ldg8(q1), qf11 = ldg8(q1 + 32), qf12 = ldg8(q1 + 64);

    const int m0 = ch * mper;
    const int m1 = (m0 + mper < MTOT) ? (m0 + mper) : MTOT;
    const int ntiles = (m1 > m0) ? ((m1 - m0) >> 6) : 0;

    // KC staging offsets (inverse-swizzled global source, linear LDS dest)
    int kgo[4];
#pragma unroll
    for (int i = 0; i < 4; ++i) {
        int ol = w * 4096 + i * 1024 + lane * 16;
        int row = ol >> 8, c = (ol >> 4) & 15;
        int u = c ^ (row & 7); if (u >= 12) u = 0;       // chunks >=12 never read
        kgo[i] = row * 192 + u * 16;
    }

    f32x4 a00 = {0,0,0,0}, a01 = {0,0,0,0}, a02 = {0,0,0,0}, a03 = {0,0,0,0};
    f32x4 a10 = {0,0,0,0}, a11 = {0,0,0,0}, a12 = {0,0,0,0}, a13 = {0,0,0,0};
    float ls[8] = {0,0,0,0,0,0,0,0};

    if (ntiles > 0) {
        const char* kb = (const char*)KCg + (size_t)m0 * 192;
#pragma unroll
        for (int i = 0; i < 4; ++i) glds16(kb + kgo[i], (char*)KCs[0] + w * 4096 + i * 1024);
    }
    __syncthreads();

    // per-lane V base (interleaved Vt, read straight from global/L2)
    const u16* vb0 = Vtg + (size_t)l15 * MTOT + m0 + g * 8;
    char* pbw = (char*)Pb[w];
    const int xr = l15 & 7;

    int cur = 0;
    for (int t = 0; t < ntiles; ++t) {
        if (t + 1 < ntiles) {
            int mt = m0 + ((t + 1) << 6);
            const char* kb = (const char*)KCg + (size_t)mt * 192;
            int nb = cur ^ 1;
#pragma unroll
            for (int i = 0; i < 4; ++i) glds16(kb + kgo[i], (char*)KCs[nb] + w * 4096 + i * 1024);
        }
        // V fragments for both 32-m steps, from L2 (issued early, hidden by kf+S phase)
        const u16* vb = vb0 + (t << 6);
        bf16x8 vf[2][4];
#pragma unroll
        for (int j = 0; j < 2; ++j)
#pragma unroll
            for (int d4 = 0; d4 < 4; ++d4)
                vf[j][d4] = ldg8(vb + (size_t)(d4 * 16) * MTOT + j * 32);

        const char* kcb = (const char*)KCs[cur];

#pragma unroll
        for (int j = 0; j < 2; ++j) {               // two 32-m steps per 64-m tile
            bf16x8 kf[2][3];
#pragma unroll
            for (int s = 0; s < 2; ++s)
#pragma unroll
                for (int ks = 0; ks < 3; ++ks) {
                    int row = j * 32 + s * 16 + l15;
                    kf[s][ks] = *reinterpret_cast<const bf16x8*>(kcb + row * 256 + (((ks * 4 + g) ^ xr) << 4));
                }

            // S = Qc · KC^T : lane holds S row b = g*4+r (per b-subtile), col m' = l15 / 16+l15
            f32x4 S00 = {0,0,0,0}, S01 = {0,0,0,0}, S10 = {0,0,0,0}, S11 = {0,0,0,0};
            S00 = MFMA(qf00, kf[0][0], S00,0,0,0); S00 = MFMA(qf01, kf[0][1], S00,0,0,0); S00 = MFMA(qf02, kf[0][2], S00,0,0,0);
            S01 = MFMA(qf00, kf[1][0], S01,0,0,0); S01 = MFMA(qf01, kf[1][1], S01,0,0,0); S01 = MFMA(qf02, kf[1][2], S01,0,0,0);
            S10 = MFMA(qf10, kf[0][0], S10,0,0,0); S10 = MFMA(qf11, kf[0][1], S10,0,0,0); S10 = MFMA(qf12, kf[0][2], S10,0,0,0);
            S11 = MFMA(qf10, kf[1][0], S11,0,0,0); S11 = MFMA(qf11, kf[1][1], S11,0,0,0); S11 = MFMA(qf12, kf[1][2], S11,0,0,0);

#pragma unroll
            for (int r = 0; r < 4; ++r) {
                float p00 = exp2f(S00[r]), p01 = exp2f(S01[r]);
                float p10 = exp2f(S10[r]), p11 = exp2f(S11[r]);
                ls[r]     += p00 + p01;
                ls[4 + r] += p10 + p11;
                int row0 = g * 4 + r, row1 = 16 + g * 4 + r;
                *(u32*)(pbw + row0 * 80 + l15 * 4) = pk2(p00, p01);   // pair (m'=l15, m'=16+l15)
                *(u32*)(pbw + row1 * 80 + l15 * 4) = pk2(p10, p11);
            }
            bf16x8 pa0 = *reinterpret_cast<const bf16x8*>(pbw + l15 * 80        + g * 16);
            bf16x8 pa1 = *reinterpret_cast<const bf16x8*>(pbw + (16 + l15) * 80 + g * 16);

            a00 = MFMA(pa0, vf[j][0], a00,0,0,0); a01 = MFMA(pa0, vf[j][1], a01,0,0,0);
            a02 = MFMA(pa0, vf[j][2], a02,0,0,0); a03 = MFMA(pa0, vf[j][3], a03,0,0,0);
            a10 = MFMA(pa1, vf[j][0], a10,0,0,0); a11 = MFMA(pa1, vf[j][1], a11,0,0,0);
            a12 = MFMA(pa1, vf[j][2], a12,0,0,0); a13 = MFMA(pa1, vf[j][3], a13,0,0,0);
        }
        __syncthreads();
        cur ^= 1;
    }

    // lsum: reduce over the 16 m'-lanes
#pragma unroll
    for (int i = 0; i < 8; ++i) {
        float v = ls[i];
        v += __shfl_xor(v, 1, 16); v += __shfl_xor(v, 2, 16);
        v += __shfl_xor(v, 4, 16); v += __shfl_xor(v, 8, 16);
        ls[i] = v;
    }
    if (l15 == 0) {
        f32x4 s0 = {ls[0], ls[1], ls[2], ls[3]};
        f32x4 s1 = {ls[4], ls[5], ls[6], ls[7]};
        *reinterpret_cast<f32x4*>(pl + (size_t)ch * BTOT + rbase + g * 4)      = s0;
        *reinterpret_cast<f32x4*>(pl + (size_t)ch * BTOT + rbase + 16 + g * 4) = s1;
    }

    // pacc[ch][d][b]: lane col d = d4*16+l15; rows b = rbase + sb*16 + g*4 + r
    float* b0 = pacc + ((size_t)ch * DD + l15) * BTOT + rbase + g * 4;
    *reinterpret_cast<f32x4*>(b0 + (size_t)0  * BTOT) = a00;
    *reinterpret_cast<f32x4*>(b0 + (size_t)16 * BTOT) = a01;
    *reinterpret_cast<f32x4*>(b0 + (size_t)32 * BTOT) = a02;
    *reinterpret_cast<f32x4*>(b0 + (size_t)48 * BTOT) = a03;
    float* b1 = b0 + 16;
    *reinterpret_cast<f32x4*>(b1 + (size_t)0  * BTOT) = a10;
    *reinterpret_cast<f32x4*>(b1 + (size_t)16 * BTOT) = a11;
    *reinterpret_cast<f32x4*>(b1 + (size_t)32 * BTOT) = a12;
    *reinterpret_cast<f32x4*>(b1 + (size_t)48 * BTOT) = a13;
}

// ---------------- combine ----------------
__global__ __launch_bounds__(256)
void epmem_combine(const float* __restrict__ pl,
                   const float* __restrict__ pacc,
                   float* __restrict__ out, int split)
{
    int t = blockIdx.x * 256 + threadIdx.x;
    if (t >= DD * BTOT) return;
    int d = t >> 10;
    int b = t & 1023;
    float lssum = 0.0f;
    for (int ch = 0; ch < split; ++ch) lssum += pl[(size_t)ch * BTOT + b];
    float v = 0.0f;
    for (int ch = 0; ch < split; ++ch) v += pacc[((size_t)ch * DD + d) * BTOT + b];
    out[(size_t)b * DD + d] = v / lssum;
}

extern "C" void kernel_launch(void* const* d_in, const int* in_sizes, int n_in,
                              void* d_out, int out_size, void* d_ws, size_t ws_size,
                              hipStream_t stream)
{
    const float* q    = (const float*)d_in[0];
    const float* ctx  = (const float*)d_in[1];
    const float* K    = (const float*)d_in[2];
    const float* V    = (const float*)d_in[3];
    const float* CT   = (const float*)d_in[4];
    const float* TS   = (const float*)d_in[5];
    const int*   mask = (const int*)d_in[6];

    char* wsb = (char*)d_ws;
    u16* Qc = (u16*)(wsb);                                // 1024*96*2   = 196608
    u16* KC = (u16*)(wsb + 196608);                       // 65536*96*2  = 12582912
    u16* Vt = (u16*)(wsb + 196608 + 12582912);            // 64*65536*2  = 8388608
    size_t fixed = 196608 + 12582912 + 8388608;           // 21168128

    size_t chunk = (size_t)BTOT * (DD + 1) * sizeof(float);   // 266240
    int SPLIT = (int)((ws_size - fixed) / chunk);
    if (SPLIT > 96) SPLIT = 96;                            // NB=768 = 3 blocks/CU
    SPLIT &= ~7;
    if (SPLIT < 8) SPLIT = 8;

    float* pl   = (float*)(wsb + fixed);                  // [SPLIT][1024]
    float* pacc = pl + (size_t)SPLIT * BTOT;              // [SPLIT][64][1024]

    int mper = ((MTOT + SPLIT - 1) / SPLIT + 63) & ~63;   // multiple of 64

    prep_all<<<NROWBLK + NVTBLK, 256, 0, stream>>>(q, ctx, K, CT, TS, mask, V, Qc, KC, Vt);

    int NB = 8 * SPLIT;
    epmem_mfma<<<NB, 256, 0, stream>>>(Qc, KC, Vt, pl, pacc, mper, NB);

    epmem_combine<<<(DD * BTOT + 255) / 256, 256, 0, stream>>>(pl, pacc, (float*)d_out, SPLIT);
}

// Round 11
// 101.057 us; speedup vs baseline: 1.0908x; 1.0908x over previous
//
#include <hip/hip_runtime.h>

typedef float f32x4 __attribute__((ext_vector_type(4)));
typedef __bf16 bf16x8 __attribute__((ext_vector_type(8)));
typedef unsigned int u32;
typedef unsigned short u16;

#define MTOT 65536
#define BTOT 1024
#define DD 64
#define LOG2E 1.44269504088896340736f
#define MFMA __builtin_amdgcn_mfma_f32_16x16x32_bf16

#define NROWBLK ((MTOT + BTOT) * 24 / 256)   // 6240
#define NVTBLK  (MTOT / 64)                  // 1024

__device__ __forceinline__ u16 f2bf(float f) { return __builtin_bit_cast(u16, (__bf16)f); }
__device__ __forceinline__ u32 pk2(float a, float b) {
    return (u32)f2bf(a) | ((u32)f2bf(b) << 16);
}
__device__ __forceinline__ bf16x8 ldg8(const u16* p) { return *reinterpret_cast<const bf16x8*>(p); }
__device__ __forceinline__ void glds16(const void* g, void* l) {
    __builtin_amdgcn_global_load_lds((const __attribute__((address_space(1))) u32*)g,
                                     (__attribute__((address_space(3))) u32*)l, 16, 0, 0);
}

// ---------------- fused precompute: Qc/KC rows + interleaved Vt ----------------
__global__ __launch_bounds__(256)
void prep_all(const float* __restrict__ q, const float* __restrict__ ctx,
              const float* __restrict__ K, const float* __restrict__ CT,
              const float* __restrict__ TS, const int* __restrict__ mask,
              const float* __restrict__ V,
              u16* __restrict__ Qc, u16* __restrict__ KC, u16* __restrict__ Vt)
{
    __shared__ u16 L[64][68];
    const int blk = blockIdx.x, t = threadIdx.x;

    if (blk < NROWBLK) {
        const int R = MTOT + BTOT;
        int gid = blk * 256 + t;                   // R*24 total, exact
        float4 v = {0.f, 0.f, 0.f, 0.f};
        u16* dst;
        if (gid < R * 16) {                        // feature cols 0..63
            int row = gid >> 4, qd = gid & 15;
            bool isQ = row >= MTOT;
            int r2 = isQ ? row - MTOT : row;
            v = *reinterpret_cast<const float4*>((isQ ? q : K) + (size_t)r2 * 64 + qd * 4);
            if (isQ) { v.x *= LOG2E; v.y *= LOG2E; v.z *= LOG2E; v.w *= LOG2E; }
            dst = (isQ ? Qc : KC) + (size_t)r2 * 96 + qd * 4;
        } else if (gid < R * 20) {                 // context cols 64..79
            int i = gid - R * 16;
            int row = i >> 2, qd = i & 3;
            bool isQ = row >= MTOT;
            int r2 = isQ ? row - MTOT : row;
            v = *reinterpret_cast<const float4*>((isQ ? ctx : CT) + (size_t)r2 * 16 + qd * 4);
            if (isQ) { const float s = 0.5f * LOG2E; v.x *= s; v.y *= s; v.z *= s; v.w *= s; }
            dst = (isQ ? Qc : KC) + (size_t)r2 * 96 + 64 + qd * 4;
        } else {                                   // bias col 80 + pad 81..95
            int i = gid - R * 20;
            int row = i >> 2, qd = i & 3;
            bool isQ = row >= MTOT;
            int r2 = isQ ? row - MTOT : row;
            if (qd == 0)
                v.x = isQ ? LOG2E
                          : (mask[r2] ? 0.3f * __expf(-0.1f * (1000.0f - TS[r2])) : -100.0f);
            dst = (isQ ? Qc : KC) + (size_t)r2 * 96 + 80 + qd * 4;
        }
        ushort4 o = { f2bf(v.x), f2bf(v.y), f2bf(v.z), f2bf(v.w) };
        *reinterpret_cast<ushort4*>(dst) = o;
        return;
    }

    // ---- Vt part: interleaved transpose (pairs (x, 16+x)) ----
    const int m0 = (blk - NROWBLK) * 64;
#pragma unroll
    for (int p = 0; p < 4; ++p) {
        int fi = t + p * 256;              // float4 index 0..1023
        int mi = fi >> 4, di = (fi & 15) << 2;
        float4 v = *reinterpret_cast<const float4*>(V + (size_t)(m0 + mi) * 64 + di);
        ushort4 o = { f2bf(v.x), f2bf(v.y), f2bf(v.z), f2bf(v.w) };
        *reinterpret_cast<ushort4*>(&L[mi][di]) = o;
    }
    __syncthreads();
    const int d = t >> 2, seg = t & 3;
    u32 pk[8];
#pragma unroll
    for (int pr = 0; pr < 8; ++pr) {
        int c0 = seg * 16 + pr * 2;
        int g32 = c0 >> 5;
        int i0 = c0 & 31, i1 = (c0 + 1) & 31;
        int mp0 = g32 * 32 + (i0 >> 1) + (i0 & 1) * 16;   // interleave
        int mp1 = g32 * 32 + (i1 >> 1) + (i1 & 1) * 16;
        pk[pr] = (u32)L[mp0][d] | ((u32)L[mp1][d] << 16);
    }
    uint4 A = {pk[0], pk[1], pk[2], pk[3]}, B4 = {pk[4], pk[5], pk[6], pk[7]};
    u16* dst = Vt + (size_t)d * MTOT + m0 + seg * 16;
    *reinterpret_cast<uint4*>(dst)     = A;
    *reinterpret_cast<uint4*>(dst + 8) = B4;
}

// ---------------- main: KC+V via LDS double-buffer (glds), P via swizzled per-wave LDS ----------------
__global__ __launch_bounds__(256, 3)
void epmem_mfma(const u16* __restrict__ Qc, const u16* __restrict__ KCg,
                const u16* __restrict__ Vtg,
                float* __restrict__ pl, float* __restrict__ pacc,
                int mper, int NB)
{
    __shared__ __align__(16) u16 KCs[2][64 * 96];    // 24 KB: [m 64][192B rows, chunk-swizzled]
    __shared__ __align__(16) u16 Vts[2][64 * 64];    // 16 KB: [d 64][128B rows, chunk-swizzled]
    __shared__ __align__(16) u16 Pb[4][32][40];      // 10 KB: 80B rows, chunk-swizzled

    const int tid = threadIdx.x;
    const int w = tid >> 6, lane = tid & 63;
    const int l15 = lane & 15, g = lane >> 4;

    const int bid = blockIdx.x;
    const int o = (bid & 7) * (NB >> 3) + (bid >> 3);     // XCD-bijective (NB % 8 == 0)
    const int rt = o & 7, ch = o >> 3;
    const int rbase = rt * 128 + w * 32;

    // Q fragments (2 b-subtiles x 3 k-chunks), LOG2E pre-scaled
    const u16* q0 = Qc + (size_t)(rbase + l15) * 96 + g * 8;
    const bf16x8 qf00 = ldg8(q0), qf01 = ldg8(q0 + 32), qf02 = ldg8(q0 + 64);
    const u16* q1 = q0 + 16 * 96;
    const bf16x8 qf10 = ldg8(q1), qf11 = ldg8(q1 + 32), qf12 = ldg8(q1 + 64);

    const int m0 = ch * mper;
    const int m1 = (m0 + mper < MTOT) ? (m0 + mper) : MTOT;
    const int ntiles = (m1 > m0) ? ((m1 - m0) >> 6) : 0;

    // KC staging offsets: LDS linear <- inverse-swizzled global (192B rows, 12 chunks)
    int kgo[3];
#pragma unroll
    for (int i = 0; i < 3; ++i) {
        int ol = w * 3072 + i * 1024 + lane * 16;
        int row = ol / 192;
        int c = (ol - row * 192) >> 4;                   // 0..11
        int u = (c < 8) ? (c ^ (row & 7)) : (8 + ((c & 3) ^ (row & 3)));
        kgo[i] = row * 192 + u * 16;
    }
    // V staging offsets (128B rows, 8 chunks)
    int vgo[2];
#pragma unroll
    for (int i = 0; i < 2; ++i) {
        int ol = w * 2048 + i * 1024 + lane * 16;
        int row = ol >> 7, c = (ol >> 4) & 7;
        int u = c ^ (row & 7);
        vgo[i] = row * (MTOT * 2) + u * 16;
    }

    f32x4 a00 = {0,0,0,0}, a01 = {0,0,0,0}, a02 = {0,0,0,0}, a03 = {0,0,0,0};
    f32x4 a10 = {0,0,0,0}, a11 = {0,0,0,0}, a12 = {0,0,0,0}, a13 = {0,0,0,0};
    float ls[8] = {0,0,0,0,0,0,0,0};

    if (ntiles > 0) {
        const char* kb = (const char*)KCg + (size_t)m0 * 192;
        const char* vb = (const char*)Vtg + (size_t)m0 * 2;
#pragma unroll
        for (int i = 0; i < 3; ++i) glds16(kb + kgo[i], (char*)KCs[0] + w * 3072 + i * 1024);
#pragma unroll
        for (int i = 0; i < 2; ++i) glds16(vb + vgo[i], (char*)Vts[0] + w * 2048 + i * 1024);
    }
    __syncthreads();

    char* pbw = (char*)Pb[w];
    const int xr = l15 & 7;
    const int x3 = l15 & 3;

    int cur = 0;
    for (int t = 0; t < ntiles; ++t) {
        if (t + 1 < ntiles) {       // fire-and-forget next-tile stage (in flight across compute)
            int mt = m0 + ((t + 1) << 6);
            const char* kb = (const char*)KCg + (size_t)mt * 192;
            const char* vb = (const char*)Vtg + (size_t)mt * 2;
            int nb = cur ^ 1;
#pragma unroll
            for (int i = 0; i < 3; ++i) glds16(kb + kgo[i], (char*)KCs[nb] + w * 3072 + i * 1024);
#pragma unroll
            for (int i = 0; i < 2; ++i) glds16(vb + vgo[i], (char*)Vts[nb] + w * 2048 + i * 1024);
        }
        const char* kcb = (const char*)KCs[cur];
        const char* vtb = (const char*)Vts[cur];

#pragma unroll
        for (int j = 0; j < 2; ++j) {               // two 32-m steps per 64-m tile
            bf16x8 kf[2][3];
#pragma unroll
            for (int s = 0; s < 2; ++s) {
                int row = j * 32 + s * 16 + l15;
                kf[s][0] = *reinterpret_cast<const bf16x8*>(kcb + row * 192 + (((0 + g) ^ xr) << 4));
                kf[s][1] = *reinterpret_cast<const bf16x8*>(kcb + row * 192 + (((4 + g) ^ xr) << 4));
                kf[s][2] = *reinterpret_cast<const bf16x8*>(kcb + row * 192 + ((8 + (g ^ x3)) << 4));
            }
            bf16x8 vf[4];
#pragma unroll
            for (int d4 = 0; d4 < 4; ++d4) {
                int row = d4 * 16 + l15;
                vf[d4] = *reinterpret_cast<const bf16x8*>(vtb + row * 128 + (((j * 4 + g) ^ xr) << 4));
            }

            // S = Qc · KC^T : lane holds S row b = g*4+r (per b-subtile), col m' = l15 / 16+l15
            f32x4 S00 = {0,0,0,0}, S01 = {0,0,0,0}, S10 = {0,0,0,0}, S11 = {0,0,0,0};
            S00 = MFMA(qf00, kf[0][0], S00,0,0,0); S00 = MFMA(qf01, kf[0][1], S00,0,0,0); S00 = MFMA(qf02, kf[0][2], S00,0,0,0);
            S01 = MFMA(qf00, kf[1][0], S01,0,0,0); S01 = MFMA(qf01, kf[1][1], S01,0,0,0); S01 = MFMA(qf02, kf[1][2], S01,0,0,0);
            S10 = MFMA(qf10, kf[0][0], S10,0,0,0); S10 = MFMA(qf11, kf[0][1], S10,0,0,0); S10 = MFMA(qf12, kf[0][2], S10,0,0,0);
            S11 = MFMA(qf10, kf[1][0], S11,0,0,0); S11 = MFMA(qf11, kf[1][1], S11,0,0,0); S11 = MFMA(qf12, kf[1][2], S11,0,0,0);

#pragma unroll
            for (int r = 0; r < 4; ++r) {
                float p00 = exp2f(S00[r]), p01 = exp2f(S01[r]);
                float p10 = exp2f(S10[r]), p11 = exp2f(S11[r]);
                ls[r]     += p00 + p01;
                ls[4 + r] += p10 + p11;
                int row0 = g * 4 + r, row1 = 16 + g * 4 + r;   // row&3 == r
                int cw = (((l15 >> 2) ^ r) << 4) | ((l15 & 3) << 2);
                *(u32*)(pbw + row0 * 80 + cw) = pk2(p00, p01);   // pair (m'=l15, 16+l15)
                *(u32*)(pbw + row1 * 80 + cw) = pk2(p10, p11);
            }
            bf16x8 pa0 = *reinterpret_cast<const bf16x8*>(pbw + l15 * 80        + ((g ^ x3) << 4));
            bf16x8 pa1 = *reinterpret_cast<const bf16x8*>(pbw + (16 + l15) * 80 + ((g ^ x3) << 4));

            a00 = MFMA(pa0, vf[0], a00,0,0,0); a01 = MFMA(pa0, vf[1], a01,0,0,0);
            a02 = MFMA(pa0, vf[2], a02,0,0,0); a03 = MFMA(pa0, vf[3], a03,0,0,0);
            a10 = MFMA(pa1, vf[0], a10,0,0,0); a11 = MFMA(pa1, vf[1], a11,0,0,0);
            a12 = MFMA(pa1, vf[2], a12,0,0,0); a13 = MFMA(pa1, vf[3], a13,0,0,0);
        }
        __syncthreads();
        cur ^= 1;
    }

    // lsum: reduce over the 16 m'-lanes
#pragma unroll
    for (int i = 0; i < 8; ++i) {
        float v = ls[i];
        v += __shfl_xor(v, 1, 16); v += __shfl_xor(v, 2, 16);
        v += __shfl_xor(v, 4, 16); v += __shfl_xor(v, 8, 16);
        ls[i] = v;
    }
    if (l15 == 0) {
        f32x4 s0 = {ls[0], ls[1], ls[2], ls[3]};
        f32x4 s1 = {ls[4], ls[5], ls[6], ls[7]};
        *reinterpret_cast<f32x4*>(pl + (size_t)ch * BTOT + rbase + g * 4)      = s0;
        *reinterpret_cast<f32x4*>(pl + (size_t)ch * BTOT + rbase + 16 + g * 4) = s1;
    }

    // pacc[ch][d][b]: lane col d = d4*16+l15; rows b = rbase + sb*16 + g*4 + r
    float* b0 = pacc + ((size_t)ch * DD + l15) * BTOT + rbase + g * 4;
    *reinterpret_cast<f32x4*>(b0 + (size_t)0  * BTOT) = a00;
    *reinterpret_cast<f32x4*>(b0 + (size_t)16 * BTOT) = a01;
    *reinterpret_cast<f32x4*>(b0 + (size_t)32 * BTOT) = a02;
    *reinterpret_cast<f32x4*>(b0 + (size_t)48 * BTOT) = a03;
    float* b1 = b0 + 16;
    *reinterpret_cast<f32x4*>(b1 + (size_t)0  * BTOT) = a10;
    *reinterpret_cast<f32x4*>(b1 + (size_t)16 * BTOT) = a11;
    *reinterpret_cast<f32x4*>(b1 + (size_t)32 * BTOT) = a12;
    *reinterpret_cast<f32x4*>(b1 + (size_t)48 * BTOT) = a13;
}

// ---------------- combine ----------------
__global__ __launch_bounds__(256)
void epmem_combine(const float* __restrict__ pl,
                   const float* __restrict__ pacc,
                   float* __restrict__ out, int split)
{
    int t = blockIdx.x * 256 + threadIdx.x;
    if (t >= DD * BTOT) return;
    int d = t >> 10;
    int b = t & 1023;
    float lssum = 0.0f;
    for (int ch = 0; ch < split; ++ch) lssum += pl[(size_t)ch * BTOT + b];
    float v = 0.0f;
    for (int ch = 0; ch < split; ++ch) v += pacc[((size_t)ch * DD + d) * BTOT + b];
    out[(size_t)b * DD + d] = v / lssum;
}

extern "C" void kernel_launch(void* const* d_in, const int* in_sizes, int n_in,
                              void* d_out, int out_size, void* d_ws, size_t ws_size,
                              hipStream_t stream)
{
    const float* q    = (const float*)d_in[0];
    const float* ctx  = (const float*)d_in[1];
    const float* K    = (const float*)d_in[2];
    const float* V    = (const float*)d_in[3];
    const float* CT   = (const float*)d_in[4];
    const float* TS   = (const float*)d_in[5];
    const int*   mask = (const int*)d_in[6];

    char* wsb = (char*)d_ws;
    u16* Qc = (u16*)(wsb);                                // 1024*96*2   = 196608
    u16* KC = (u16*)(wsb + 196608);                       // 65536*96*2  = 12582912
    u16* Vt = (u16*)(wsb + 196608 + 12582912);            // 64*65536*2  = 8388608
    size_t fixed = 196608 + 12582912 + 8388608;           // 21168128

    size_t chunk = (size_t)BTOT * (DD + 1) * sizeof(float);   // 266240
    int SPLIT = (int)((ws_size - fixed) / chunk);
    if (SPLIT > 96) SPLIT = 96;                            // NB=768 = 3 blocks/CU
    SPLIT &= ~7;
    if (SPLIT < 8) SPLIT = 8;

    float* pl   = (float*)(wsb + fixed);                  // [SPLIT][1024]
    float* pacc = pl + (size_t)SPLIT * BTOT;              // [SPLIT][64][1024]

    int mper = ((MTOT + SPLIT - 1) / SPLIT + 63) & ~63;   // multiple of 64

    prep_all<<<NROWBLK + NVTBLK, 256, 0, stream>>>(q, ctx, K, CT, TS, mask, V, Qc, KC, Vt);

    int NB = 8 * SPLIT;
    epmem_mfma<<<NB, 256, 0, stream>>>(Qc, KC, Vt, pl, pacc, mper, NB);

    epmem_combine<<<(DD * BTOT + 255) / 256, 256, 0, stream>>>(pl, pacc, (float*)d_out, SPLIT);
}

// Round 12
// 63.147 us; speedup vs baseline: 1.7456x; 1.6003x over previous
//
#include <hip/hip_runtime.h>

typedef float f32x4 __attribute__((ext_vector_type(4)));
typedef __bf16 bf16x8 __attribute__((ext_vector_type(8)));
typedef unsigned int u32;
typedef unsigned short u16;

#define MTOT 65536
#define BTOT 1024
#define DD 64
#define LOG2E 1.44269504088896340736f
#define MFMA __builtin_amdgcn_mfma_f32_16x16x32_bf16

#define NROWBLK ((MTOT + BTOT) * 24 / 256)   // 6240
#define NVTBLK  (MTOT / 64)                  // 1024
#define ESPACE  (DD * BTOT + BTOT)           // 66560
#define NSLICE  8

__device__ __forceinline__ u16 f2bf(float f) { return __builtin_bit_cast(u16, (__bf16)f); }
__device__ __forceinline__ u32 pk2(float a, float b) {
    return (u32)f2bf(a) | ((u32)f2bf(b) << 16);
}
__device__ __forceinline__ bf16x8 ldg8(const u16* p) { return *reinterpret_cast<const bf16x8*>(p); }
__device__ __forceinline__ void glds16(const void* g, void* l) {
    __builtin_amdgcn_global_load_lds((const __attribute__((address_space(1))) u32*)g,
                                     (__attribute__((address_space(3))) u32*)l, 16, 0, 0);
}

// ---------------- fused precompute: Qc/KC rows + interleaved Vt ----------------
__global__ __launch_bounds__(256)
void prep_all(const float* __restrict__ q, const float* __restrict__ ctx,
              const float* __restrict__ K, const float* __restrict__ CT,
              const float* __restrict__ TS, const int* __restrict__ mask,
              const float* __restrict__ V,
              u16* __restrict__ Qc, u16* __restrict__ KC, u16* __restrict__ Vt)
{
    __shared__ u16 L[64][68];
    const int blk = blockIdx.x, t = threadIdx.x;

    if (blk < NROWBLK) {
        const int R = MTOT + BTOT;
        int gid = blk * 256 + t;                   // R*24 total, exact
        float4 v = {0.f, 0.f, 0.f, 0.f};
        u16* dst;
        if (gid < R * 16) {                        // feature cols 0..63
            int row = gid >> 4, qd = gid & 15;
            bool isQ = row >= MTOT;
            int r2 = isQ ? row - MTOT : row;
            v = *reinterpret_cast<const float4*>((isQ ? q : K) + (size_t)r2 * 64 + qd * 4);
            if (isQ) { v.x *= LOG2E; v.y *= LOG2E; v.z *= LOG2E; v.w *= LOG2E; }
            dst = (isQ ? Qc : KC) + (size_t)r2 * 96 + qd * 4;
        } else if (gid < R * 20) {                 // context cols 64..79
            int i = gid - R * 16;
            int row = i >> 2, qd = i & 3;
            bool isQ = row >= MTOT;
            int r2 = isQ ? row - MTOT : row;
            v = *reinterpret_cast<const float4*>((isQ ? ctx : CT) + (size_t)r2 * 16 + qd * 4);
            if (isQ) { const float s = 0.5f * LOG2E; v.x *= s; v.y *= s; v.z *= s; v.w *= s; }
            dst = (isQ ? Qc : KC) + (size_t)r2 * 96 + 64 + qd * 4;
        } else {                                   // bias col 80 + pad 81..95
            int i = gid - R * 20;
            int row = i >> 2, qd = i & 3;
            bool isQ = row >= MTOT;
            int r2 = isQ ? row - MTOT : row;
            if (qd == 0)
                v.x = isQ ? LOG2E
                          : (mask[r2] ? 0.3f * __expf(-0.1f * (1000.0f - TS[r2])) : -100.0f);
            dst = (isQ ? Qc : KC) + (size_t)r2 * 96 + 80 + qd * 4;
        }
        ushort4 o = { f2bf(v.x), f2bf(v.y), f2bf(v.z), f2bf(v.w) };
        *reinterpret_cast<ushort4*>(dst) = o;
        return;
    }

    // ---- Vt part: interleaved transpose (pairs (x, 16+x)) ----
    const int m0 = (blk - NROWBLK) * 64;
#pragma unroll
    for (int p = 0; p < 4; ++p) {
        int fi = t + p * 256;              // float4 index 0..1023
        int mi = fi >> 4, di = (fi & 15) << 2;
        float4 v = *reinterpret_cast<const float4*>(V + (size_t)(m0 + mi) * 64 + di);
        ushort4 o = { f2bf(v.x), f2bf(v.y), f2bf(v.z), f2bf(v.w) };
        *reinterpret_cast<ushort4*>(&L[mi][di]) = o;
    }
    __syncthreads();
    const int d = t >> 2, seg = t & 3;
    u32 pk[8];
#pragma unroll
    for (int pr = 0; pr < 8; ++pr) {
        int c0 = seg * 16 + pr * 2;
        int g32 = c0 >> 5;
        int i0 = c0 & 31, i1 = (c0 + 1) & 31;
        int mp0 = g32 * 32 + (i0 >> 1) + (i0 & 1) * 16;   // interleave
        int mp1 = g32 * 32 + (i1 >> 1) + (i1 & 1) * 16;
        pk[pr] = (u32)L[mp0][d] | ((u32)L[mp1][d] << 16);
    }
    uint4 A = {pk[0], pk[1], pk[2], pk[3]}, B4 = {pk[4], pk[5], pk[6], pk[7]};
    u16* dst = Vt + (size_t)d * MTOT + m0 + seg * 16;
    *reinterpret_cast<uint4*>(dst)     = A;
    *reinterpret_cast<uint4*>(dst + 8) = B4;
}

// ---------------- main: KC+V via LDS double-buffer (glds), P via swizzled per-wave LDS ----------------
__global__ __launch_bounds__(256, 3)
void epmem_mfma(const u16* __restrict__ Qc, const u16* __restrict__ KCg,
                const u16* __restrict__ Vtg,
                float* __restrict__ pl, float* __restrict__ pacc,
                int mper, int NB)
{
    __shared__ __align__(16) u16 KCs[2][64 * 96];    // 24 KB
    __shared__ __align__(16) u16 Vts[2][64 * 64];    // 16 KB
    __shared__ __align__(16) u16 Pb[4][32][40];      // 10 KB

    const int tid = threadIdx.x;
    const int w = tid >> 6, lane = tid & 63;
    const int l15 = lane & 15, g = lane >> 4;

    const int bid = blockIdx.x;
    const int o = (bid & 7) * (NB >> 3) + (bid >> 3);     // XCD-bijective (NB % 8 == 0)
    const int rt = o & 7, ch = o >> 3;
    const int rbase = rt * 128 + w * 32;

    const u16* q0 = Qc + (size_t)(rbase + l15) * 96 + g * 8;
    const bf16x8 qf00 = ldg8(q0), qf01 = ldg8(q0 + 32), qf02 = ldg8(q0 + 64);
    const u16* q1 = q0 + 16 * 96;
    const bf16x8 qf10 = ldg8(q1), qf11 = ldg8(q1 + 32), qf12 = ldg8(q1 + 64);

    const int m0 = ch * mper;
    const int m1 = (m0 + mper < MTOT) ? (m0 + mper) : MTOT;
    const int ntiles = (m1 > m0) ? ((m1 - m0) >> 6) : 0;

    int kgo[3];
#pragma unroll
    for (int i = 0; i < 3; ++i) {
        int ol = w * 3072 + i * 1024 + lane * 16;
        int row = ol / 192;
        int c = (ol - row * 192) >> 4;                   // 0..11
        int u = (c < 8) ? (c ^ (row & 7)) : (8 + ((c & 3) ^ (row & 3)));
        kgo[i] = row * 192 + u * 16;
    }
    int vgo[2];
#pragma unroll
    for (int i = 0; i < 2; ++i) {
        int ol = w * 2048 + i * 1024 + lane * 16;
        int row = ol >> 7, c = (ol >> 4) & 7;
        int u = c ^ (row & 7);
        vgo[i] = row * (MTOT * 2) + u * 16;
    }

    f32x4 a00 = {0,0,0,0}, a01 = {0,0,0,0}, a02 = {0,0,0,0}, a03 = {0,0,0,0};
    f32x4 a10 = {0,0,0,0}, a11 = {0,0,0,0}, a12 = {0,0,0,0}, a13 = {0,0,0,0};
    float ls[8] = {0,0,0,0,0,0,0,0};

    if (ntiles > 0) {
        const char* kb = (const char*)KCg + (size_t)m0 * 192;
        const char* vb = (const char*)Vtg + (size_t)m0 * 2;
#pragma unroll
        for (int i = 0; i < 3; ++i) glds16(kb + kgo[i], (char*)KCs[0] + w * 3072 + i * 1024);
#pragma unroll
        for (int i = 0; i < 2; ++i) glds16(vb + vgo[i], (char*)Vts[0] + w * 2048 + i * 1024);
    }
    __syncthreads();

    char* pbw = (char*)Pb[w];
    const int xr = l15 & 7;
    const int x3 = l15 & 3;

    int cur = 0;
    for (int t = 0; t < ntiles; ++t) {
        if (t + 1 < ntiles) {
            int mt = m0 + ((t + 1) << 6);
            const char* kb = (const char*)KCg + (size_t)mt * 192;
            const char* vb = (const char*)Vtg + (size_t)mt * 2;
            int nb = cur ^ 1;
#pragma unroll
            for (int i = 0; i < 3; ++i) glds16(kb + kgo[i], (char*)KCs[nb] + w * 3072 + i * 1024);
#pragma unroll
            for (int i = 0; i < 2; ++i) glds16(vb + vgo[i], (char*)Vts[nb] + w * 2048 + i * 1024);
        }
        const char* kcb = (const char*)KCs[cur];
        const char* vtb = (const char*)Vts[cur];

#pragma unroll
        for (int j = 0; j < 2; ++j) {
            bf16x8 kf[2][3];
#pragma unroll
            for (int s = 0; s < 2; ++s) {
                int row = j * 32 + s * 16 + l15;
                kf[s][0] = *reinterpret_cast<const bf16x8*>(kcb + row * 192 + (((0 + g) ^ xr) << 4));
                kf[s][1] = *reinterpret_cast<const bf16x8*>(kcb + row * 192 + (((4 + g) ^ xr) << 4));
                kf[s][2] = *reinterpret_cast<const bf16x8*>(kcb + row * 192 + ((8 + (g ^ x3)) << 4));
            }
            bf16x8 vf[4];
#pragma unroll
            for (int d4 = 0; d4 < 4; ++d4) {
                int row = d4 * 16 + l15;
                vf[d4] = *reinterpret_cast<const bf16x8*>(vtb + row * 128 + (((j * 4 + g) ^ xr) << 4));
            }

            f32x4 S00 = {0,0,0,0}, S01 = {0,0,0,0}, S10 = {0,0,0,0}, S11 = {0,0,0,0};
            S00 = MFMA(qf00, kf[0][0], S00,0,0,0); S00 = MFMA(qf01, kf[0][1], S00,0,0,0); S00 = MFMA(qf02, kf[0][2], S00,0,0,0);
            S01 = MFMA(qf00, kf[1][0], S01,0,0,0); S01 = MFMA(qf01, kf[1][1], S01,0,0,0); S01 = MFMA(qf02, kf[1][2], S01,0,0,0);
            S10 = MFMA(qf10, kf[0][0], S10,0,0,0); S10 = MFMA(qf11, kf[0][1], S10,0,0,0); S10 = MFMA(qf12, kf[0][2], S10,0,0,0);
            S11 = MFMA(qf10, kf[1][0], S11,0,0,0); S11 = MFMA(qf11, kf[1][1], S11,0,0,0); S11 = MFMA(qf12, kf[1][2], S11,0,0,0);

#pragma unroll
            for (int r = 0; r < 4; ++r) {
                float p00 = exp2f(S00[r]), p01 = exp2f(S01[r]);
                float p10 = exp2f(S10[r]), p11 = exp2f(S11[r]);
                ls[r]     += p00 + p01;
                ls[4 + r] += p10 + p11;
                int row0 = g * 4 + r, row1 = 16 + g * 4 + r;
                int cw = (((l15 >> 2) ^ r) << 4) | ((l15 & 3) << 2);
                *(u32*)(pbw + row0 * 80 + cw) = pk2(p00, p01);
                *(u32*)(pbw + row1 * 80 + cw) = pk2(p10, p11);
            }
            bf16x8 pa0 = *reinterpret_cast<const bf16x8*>(pbw + l15 * 80        + ((g ^ x3) << 4));
            bf16x8 pa1 = *reinterpret_cast<const bf16x8*>(pbw + (16 + l15) * 80 + ((g ^ x3) << 4));

            a00 = MFMA(pa0, vf[0], a00,0,0,0); a01 = MFMA(pa0, vf[1], a01,0,0,0);
            a02 = MFMA(pa0, vf[2], a02,0,0,0); a03 = MFMA(pa0, vf[3], a03,0,0,0);
            a10 = MFMA(pa1, vf[0], a10,0,0,0); a11 = MFMA(pa1, vf[1], a11,0,0,0);
            a12 = MFMA(pa1, vf[2], a12,0,0,0); a13 = MFMA(pa1, vf[3], a13,0,0,0);
        }
        __syncthreads();
        cur ^= 1;
    }

#pragma unroll
    for (int i = 0; i < 8; ++i) {
        float v = ls[i];
        v += __shfl_xor(v, 1, 16); v += __shfl_xor(v, 2, 16);
        v += __shfl_xor(v, 4, 16); v += __shfl_xor(v, 8, 16);
        ls[i] = v;
    }
    if (l15 == 0) {
        f32x4 s0 = {ls[0], ls[1], ls[2], ls[3]};
        f32x4 s1 = {ls[4], ls[5], ls[6], ls[7]};
        *reinterpret_cast<f32x4*>(pl + (size_t)ch * BTOT + rbase + g * 4)      = s0;
        *reinterpret_cast<f32x4*>(pl + (size_t)ch * BTOT + rbase + 16 + g * 4) = s1;
    }

    float* b0 = pacc + ((size_t)ch * DD + l15) * BTOT + rbase + g * 4;
    *reinterpret_cast<f32x4*>(b0 + (size_t)0  * BTOT) = a00;
    *reinterpret_cast<f32x4*>(b0 + (size_t)16 * BTOT) = a01;
    *reinterpret_cast<f32x4*>(b0 + (size_t)32 * BTOT) = a02;
    *reinterpret_cast<f32x4*>(b0 + (size_t)48 * BTOT) = a03;
    float* b1 = b0 + 16;
    *reinterpret_cast<f32x4*>(b1 + (size_t)0  * BTOT) = a10;
    *reinterpret_cast<f32x4*>(b1 + (size_t)16 * BTOT) = a11;
    *reinterpret_cast<f32x4*>(b1 + (size_t)32 * BTOT) = a12;
    *reinterpret_cast<f32x4*>(b1 + (size_t)48 * BTOT) = a13;
}

// ---------------- combine stage A: slice-reduce chunks (8 slices, BW-bound) ----------------
__global__ __launch_bounds__(256)
void combineA(const float* __restrict__ pl, const float* __restrict__ pacc,
              float* __restrict__ part, int cper)
{
    int e = blockIdx.x * 256 + threadIdx.x;        // < ESPACE (66560)
    int s = blockIdx.y;
    int c0 = s * cper;
    float v0 = 0.f, v1 = 0.f;
    if (e < DD * BTOT) {                           // pacc element (contiguous: ch stride 65536)
        const float* p = pacc + (size_t)c0 * (DD * BTOT) + e;
#pragma unroll 2
        for (int i = 0; i + 1 < cper; i += 2) {
            v0 += p[(size_t)i * (DD * BTOT)];
            v1 += p[(size_t)(i + 1) * (DD * BTOT)];
        }
        if (cper & 1) v0 += p[(size_t)(cper - 1) * (DD * BTOT)];
    } else {                                       // pl element (whole blocks: wave-uniform)
        const float* p = pl + (size_t)c0 * BTOT + (e - DD * BTOT);
#pragma unroll 2
        for (int i = 0; i + 1 < cper; i += 2) {
            v0 += p[(size_t)i * BTOT];
            v1 += p[(size_t)(i + 1) * BTOT];
        }
        if (cper & 1) v0 += p[(size_t)(cper - 1) * BTOT];
    }
    part[(size_t)s * ESPACE + e] = v0 + v1;
}

// ---------------- combine stage B: sum 8 slices + divide ----------------
__global__ __launch_bounds__(256)
void combineB(const float* __restrict__ part, float* __restrict__ out)
{
    int t = blockIdx.x * 256 + threadIdx.x;        // < 65536
    int d = t >> 10, b = t & 1023;
    float v = 0.f, lssum = 0.f;
#pragma unroll
    for (int s = 0; s < NSLICE; ++s) {
        v     += part[(size_t)s * ESPACE + t];
        lssum += part[(size_t)s * ESPACE + DD * BTOT + b];
    }
    out[(size_t)b * DD + d] = v / lssum;
}

extern "C" void kernel_launch(void* const* d_in, const int* in_sizes, int n_in,
                              void* d_out, int out_size, void* d_ws, size_t ws_size,
                              hipStream_t stream)
{
    const float* q    = (const float*)d_in[0];
    const float* ctx  = (const float*)d_in[1];
    const float* K    = (const float*)d_in[2];
    const float* V    = (const float*)d_in[3];
    const float* CT   = (const float*)d_in[4];
    const float* TS   = (const float*)d_in[5];
    const int*   mask = (const int*)d_in[6];

    char* wsb = (char*)d_ws;
    u16* Qc = (u16*)(wsb);                                // 1024*96*2   = 196608
    u16* KC = (u16*)(wsb + 196608);                       // 65536*96*2  = 12582912
    u16* Vt = (u16*)(wsb + 196608 + 12582912);            // 64*65536*2  = 8388608
    size_t fixed = 196608 + 12582912 + 8388608;           // 21168128

    size_t chunk = (size_t)BTOT * (DD + 1) * sizeof(float);   // 266240
    size_t partB = (size_t)NSLICE * ESPACE * sizeof(float);   // 2129920
    int SPLIT = (int)((ws_size - fixed - partB) / chunk);
    if (SPLIT > 96) SPLIT = 96;                            // NB=768 = 3 blocks/CU
    SPLIT &= ~7;
    if (SPLIT < 8) SPLIT = 8;

    float* pl   = (float*)(wsb + fixed);                  // [SPLIT][1024]
    float* pacc = pl + (size_t)SPLIT * BTOT;              // [SPLIT][64][1024]
    float* part = pacc + (size_t)SPLIT * DD * BTOT;       // [8][66560]

    int mper = ((MTOT + SPLIT - 1) / SPLIT + 63) & ~63;   // multiple of 64
    int cper = SPLIT / NSLICE;

    prep_all<<<NROWBLK + NVTBLK, 256, 0, stream>>>(q, ctx, K, CT, TS, mask, V, Qc, KC, Vt);

    int NB = 8 * SPLIT;
    epmem_mfma<<<NB, 256, 0, stream>>>(Qc, KC, Vt, pl, pacc, mper, NB);

    dim3 gA((ESPACE + 255) / 256, NSLICE);
    combineA<<<gA, 256, 0, stream>>>(pl, pacc, part, cper);
    combineB<<<(DD * BTOT) / 256, 256, 0, stream>>>(part, (float*)d_out);
}

// Round 13
// 56.014 us; speedup vs baseline: 1.9679x; 1.1273x over previous
//
#include <hip/hip_runtime.h>

typedef float f32x4 __attribute__((ext_vector_type(4)));
typedef __bf16 bf16x8 __attribute__((ext_vector_type(8)));
typedef unsigned int u32;
typedef unsigned short u16;

#define MTOT 65536
#define BTOT 1024
#define DD 64
#define LOG2E 1.44269504088896340736f
#define MFMA __builtin_amdgcn_mfma_f32_16x16x32_bf16

#define NROWBLK ((MTOT + BTOT) * 24 / 256)   // 6240
#define NVTBLK  (MTOT / 64)                  // 1024
#define ESPACE  (DD * BTOT + BTOT)           // 66560
#define NSLICE  8

__device__ __forceinline__ u16 f2bf(float f) { return __builtin_bit_cast(u16, (__bf16)f); }
__device__ __forceinline__ u32 pk2(float a, float b) {
    return (u32)f2bf(a) | ((u32)f2bf(b) << 16);
}
__device__ __forceinline__ bf16x8 ldg8(const u16* p) { return *reinterpret_cast<const bf16x8*>(p); }
__device__ __forceinline__ float fexp2(float x) {
#if __has_builtin(__builtin_amdgcn_exp2f)
    return __builtin_amdgcn_exp2f(x);   // single v_exp_f32, compiler-known (hazard-safe)
#else
    return exp2f(x);
#endif
}
__device__ __forceinline__ void glds16(const void* g, void* l) {
    __builtin_amdgcn_global_load_lds((const __attribute__((address_space(1))) u32*)g,
                                     (__attribute__((address_space(3))) u32*)l, 16, 0, 0);
}

// ---------------- fused precompute: Qc/KC rows + interleaved Vt (unchanged, proven) ----------------
__global__ __launch_bounds__(256)
void prep_all(const float* __restrict__ q, const float* __restrict__ ctx,
              const float* __restrict__ K, const float* __restrict__ CT,
              const float* __restrict__ TS, const int* __restrict__ mask,
              const float* __restrict__ V,
              u16* __restrict__ Qc, u16* __restrict__ KC, u16* __restrict__ Vt)
{
    __shared__ u16 L[64][68];
    const int blk = blockIdx.x, t = threadIdx.x;

    if (blk < NROWBLK) {
        const int R = MTOT + BTOT;
        int gid = blk * 256 + t;                   // R*24 total, exact
        float4 v = {0.f, 0.f, 0.f, 0.f};
        u16* dst;
        if (gid < R * 16) {                        // feature cols 0..63
            int row = gid >> 4, qd = gid & 15;
            bool isQ = row >= MTOT;
            int r2 = isQ ? row - MTOT : row;
            v = *reinterpret_cast<const float4*>((isQ ? q : K) + (size_t)r2 * 64 + qd * 4);
            if (isQ) { v.x *= LOG2E; v.y *= LOG2E; v.z *= LOG2E; v.w *= LOG2E; }
            dst = (isQ ? Qc : KC) + (size_t)r2 * 96 + qd * 4;
        } else if (gid < R * 20) {                 // context cols 64..79
            int i = gid - R * 16;
            int row = i >> 2, qd = i & 3;
            bool isQ = row >= MTOT;
            int r2 = isQ ? row - MTOT : row;
            v = *reinterpret_cast<const float4*>((isQ ? ctx : CT) + (size_t)r2 * 16 + qd * 4);
            if (isQ) { const float s = 0.5f * LOG2E; v.x *= s; v.y *= s; v.z *= s; v.w *= s; }
            dst = (isQ ? Qc : KC) + (size_t)r2 * 96 + 64 + qd * 4;
        } else {                                   // bias col 80 + pad 81..95
            int i = gid - R * 20;
            int row = i >> 2, qd = i & 3;
            bool isQ = row >= MTOT;
            int r2 = isQ ? row - MTOT : row;
            if (qd == 0)
                v.x = isQ ? LOG2E
                          : (mask[r2] ? 0.3f * __expf(-0.1f * (1000.0f - TS[r2])) : -100.0f);
            dst = (isQ ? Qc : KC) + (size_t)r2 * 96 + 80 + qd * 4;
        }
        ushort4 o = { f2bf(v.x), f2bf(v.y), f2bf(v.z), f2bf(v.w) };
        *reinterpret_cast<ushort4*>(dst) = o;
        return;
    }

    // ---- Vt part: interleaved transpose (pairs (x, 16+x)) ----
    const int m0 = (blk - NROWBLK) * 64;
#pragma unroll
    for (int p = 0; p < 4; ++p) {
        int fi = t + p * 256;              // float4 index 0..1023
        int mi = fi >> 4, di = (fi & 15) << 2;
        float4 v = *reinterpret_cast<const float4*>(V + (size_t)(m0 + mi) * 64 + di);
        ushort4 o = { f2bf(v.x), f2bf(v.y), f2bf(v.z), f2bf(v.w) };
        *reinterpret_cast<ushort4*>(&L[mi][di]) = o;
    }
    __syncthreads();
    const int d = t >> 2, seg = t & 3;
    u32 pk[8];
#pragma unroll
    for (int pr = 0; pr < 8; ++pr) {
        int c0 = seg * 16 + pr * 2;
        int g32 = c0 >> 5;
        int i0 = c0 & 31, i1 = (c0 + 1) & 31;
        int mp0 = g32 * 32 + (i0 >> 1) + (i0 & 1) * 16;   // interleave
        int mp1 = g32 * 32 + (i1 >> 1) + (i1 & 1) * 16;
        pk[pr] = (u32)L[mp0][d] | ((u32)L[mp1][d] << 16);
    }
    uint4 A = {pk[0], pk[1], pk[2], pk[3]}, B4 = {pk[4], pk[5], pk[6], pk[7]};
    u16* dst = Vt + (size_t)d * MTOT + m0 + seg * 16;
    *reinterpret_cast<uint4*>(dst)     = A;
    *reinterpret_cast<uint4*>(dst + 8) = B4;
}

// ---------------- main: 64 b-rows/wave, 2-pass P, lsum via ones-MFMA ----------------
__global__ __launch_bounds__(256, 2)
void epmem_mfma(const u16* __restrict__ Qc, const u16* __restrict__ KCg,
                const u16* __restrict__ Vtg,
                float* __restrict__ pl, float* __restrict__ pacc,
                int mper, int NB)
{
    __shared__ __align__(16) u16 KCs[2][64 * 96];    // 24 KB
    __shared__ __align__(16) u16 Vts[2][64 * 64];    // 16 KB
    __shared__ __align__(16) u16 Pb[4][32][40];      // 10 KB (per wave, reused across 2 passes)

    const int tid = threadIdx.x;
    const int w = tid >> 6, lane = tid & 63;
    const int l15 = lane & 15, g = lane >> 4;

    const int bid = blockIdx.x;
    const int o = (bid & 7) * (NB >> 3) + (bid >> 3);     // XCD-bijective (NB % 8 == 0)
    const int rt = o & 3, ch = o >> 2;                    // 4 row-tiles of 256
    const int rbase = rt * 256 + w * 64;                  // wave owns 64 b-rows

    // Q fragments: 4 b-subtiles x 3 k-chunks (LOG2E pre-scaled)
    const u16* qp = Qc + (size_t)(rbase + l15) * 96 + g * 8;
    bf16x8 qf[4][3];
#pragma unroll
    for (int sb = 0; sb < 4; ++sb)
#pragma unroll
        for (int c = 0; c < 3; ++c)
            qf[sb][c] = ldg8(qp + sb * 16 * 96 + c * 32);

    const int m0 = ch * mper;
    const int m1 = (m0 + mper < MTOT) ? (m0 + mper) : MTOT;
    const int ntiles = (m1 > m0) ? ((m1 - m0) >> 6) : 0;

    // staging offsets (inverse-swizzled global source, linear LDS dest)
    int kgo[3];
#pragma unroll
    for (int i = 0; i < 3; ++i) {
        int ol = w * 3072 + i * 1024 + lane * 16;
        int row = ol / 192;
        int c = (ol - row * 192) >> 4;                   // 0..11
        int u = (c < 8) ? (c ^ (row & 7)) : (8 + ((c & 3) ^ (row & 3)));
        kgo[i] = row * 192 + u * 16;
    }
    int vgo[2];
#pragma unroll
    for (int i = 0; i < 2; ++i) {
        int ol = w * 2048 + i * 1024 + lane * 16;
        int row = ol >> 7, c = (ol >> 4) & 7;
        int u = c ^ (row & 7);
        vgo[i] = row * (MTOT * 2) + u * 16;
    }

    // constant ones B-fragment: col 0 of the 5th d-subtile = 1.0
    const u32 ow = (l15 == 0) ? 0x3F803F80u : 0u;
    const uint4 ou = {ow, ow, ow, ow};
    const bf16x8 onesf = __builtin_bit_cast(bf16x8, ou);

    f32x4 acc[4][4];
    f32x4 accl[4];
#pragma unroll
    for (int sb = 0; sb < 4; ++sb) {
        accl[sb] = (f32x4){0, 0, 0, 0};
#pragma unroll
        for (int d4 = 0; d4 < 4; ++d4) acc[sb][d4] = (f32x4){0, 0, 0, 0};
    }

    if (ntiles > 0) {
        const char* kb = (const char*)KCg + (size_t)m0 * 192;
        const char* vb = (const char*)Vtg + (size_t)m0 * 2;
#pragma unroll
        for (int i = 0; i < 3; ++i) glds16(kb + kgo[i], (char*)KCs[0] + w * 3072 + i * 1024);
#pragma unroll
        for (int i = 0; i < 2; ++i) glds16(vb + vgo[i], (char*)Vts[0] + w * 2048 + i * 1024);
    }
    __syncthreads();

    char* pbw = (char*)Pb[w];
    const int xr = l15 & 7;
    const int x3 = l15 & 3;

    int cur = 0;
    for (int t = 0; t < ntiles; ++t) {
        if (t + 1 < ntiles) {
            int mt = m0 + ((t + 1) << 6);
            const char* kb = (const char*)KCg + (size_t)mt * 192;
            const char* vb = (const char*)Vtg + (size_t)mt * 2;
            int nb = cur ^ 1;
#pragma unroll
            for (int i = 0; i < 3; ++i) glds16(kb + kgo[i], (char*)KCs[nb] + w * 3072 + i * 1024);
#pragma unroll
            for (int i = 0; i < 2; ++i) glds16(vb + vgo[i], (char*)Vts[nb] + w * 2048 + i * 1024);
        }
        const char* kcb = (const char*)KCs[cur];
        const char* vtb = (const char*)Vts[cur];

#pragma unroll
        for (int j = 0; j < 2; ++j) {               // two 32-m steps per 64-m tile
            bf16x8 kf[2][3];
#pragma unroll
            for (int s = 0; s < 2; ++s) {
                int row = j * 32 + s * 16 + l15;
                kf[s][0] = *reinterpret_cast<const bf16x8*>(kcb + row * 192 + (((0 + g) ^ xr) << 4));
                kf[s][1] = *reinterpret_cast<const bf16x8*>(kcb + row * 192 + (((4 + g) ^ xr) << 4));
                kf[s][2] = *reinterpret_cast<const bf16x8*>(kcb + row * 192 + ((8 + (g ^ x3)) << 4));
            }
            bf16x8 vf[4];
#pragma unroll
            for (int d4 = 0; d4 < 4; ++d4) {
                int row = d4 * 16 + l15;
                vf[d4] = *reinterpret_cast<const bf16x8*>(vtb + row * 128 + (((j * 4 + g) ^ xr) << 4));
            }

#pragma unroll
            for (int h = 0; h < 2; ++h) {           // two sb-pairs share kf/vf
                f32x4 S00 = {0,0,0,0}, S01 = {0,0,0,0}, S10 = {0,0,0,0}, S11 = {0,0,0,0};
                S00 = MFMA(qf[2*h][0],   kf[0][0], S00,0,0,0); S00 = MFMA(qf[2*h][1],   kf[0][1], S00,0,0,0); S00 = MFMA(qf[2*h][2],   kf[0][2], S00,0,0,0);
                S01 = MFMA(qf[2*h][0],   kf[1][0], S01,0,0,0); S01 = MFMA(qf[2*h][1],   kf[1][1], S01,0,0,0); S01 = MFMA(qf[2*h][2],   kf[1][2], S01,0,0,0);
                S10 = MFMA(qf[2*h+1][0], kf[0][0], S10,0,0,0); S10 = MFMA(qf[2*h+1][1], kf[0][1], S10,0,0,0); S10 = MFMA(qf[2*h+1][2], kf[0][2], S10,0,0,0);
                S11 = MFMA(qf[2*h+1][0], kf[1][0], S11,0,0,0); S11 = MFMA(qf[2*h+1][1], kf[1][1], S11,0,0,0); S11 = MFMA(qf[2*h+1][2], kf[1][2], S11,0,0,0);

#pragma unroll
                for (int r = 0; r < 4; ++r) {
                    float p00 = fexp2(S00[r]), p01 = fexp2(S01[r]);
                    float p10 = fexp2(S10[r]), p11 = fexp2(S11[r]);
                    int row0 = g * 4 + r, row1 = 16 + g * 4 + r;
                    int cw = (((l15 >> 2) ^ r) << 4) | ((l15 & 3) << 2);
                    *(u32*)(pbw + row0 * 80 + cw) = pk2(p00, p01);   // pair (m'=l15, 16+l15)
                    *(u32*)(pbw + row1 * 80 + cw) = pk2(p10, p11);
                }
                bf16x8 pa0 = *reinterpret_cast<const bf16x8*>(pbw + l15 * 80        + ((g ^ x3) << 4));
                bf16x8 pa1 = *reinterpret_cast<const bf16x8*>(pbw + (16 + l15) * 80 + ((g ^ x3) << 4));

                acc[2*h][0]   = MFMA(pa0, vf[0], acc[2*h][0],0,0,0);   acc[2*h][1]   = MFMA(pa0, vf[1], acc[2*h][1],0,0,0);
                acc[2*h][2]   = MFMA(pa0, vf[2], acc[2*h][2],0,0,0);   acc[2*h][3]   = MFMA(pa0, vf[3], acc[2*h][3],0,0,0);
                acc[2*h+1][0] = MFMA(pa1, vf[0], acc[2*h+1][0],0,0,0); acc[2*h+1][1] = MFMA(pa1, vf[1], acc[2*h+1][1],0,0,0);
                acc[2*h+1][2] = MFMA(pa1, vf[2], acc[2*h+1][2],0,0,0); acc[2*h+1][3] = MFMA(pa1, vf[3], acc[2*h+1][3],0,0,0);
                accl[2*h]   = MFMA(pa0, onesf, accl[2*h],0,0,0);       // lsum of quantized P
                accl[2*h+1] = MFMA(pa1, onesf, accl[2*h+1],0,0,0);
            }
        }
        __syncthreads();
        cur ^= 1;
    }

    // pl[ch][b]: lsum sits in col 0 of accl (lanes l15==0), rows b = rbase + sb*16 + g*4 + r
    if (l15 == 0) {
#pragma unroll
        for (int sb = 0; sb < 4; ++sb)
            *reinterpret_cast<f32x4*>(pl + (size_t)ch * BTOT + rbase + sb * 16 + g * 4) = accl[sb];
    }

    // pacc[ch][d][b]: lane col d = d4*16+l15; rows b = rbase + sb*16 + g*4 + r
    float* bp = pacc + ((size_t)ch * DD + l15) * BTOT + rbase + g * 4;
#pragma unroll
    for (int sb = 0; sb < 4; ++sb)
#pragma unroll
        for (int d4 = 0; d4 < 4; ++d4)
            *reinterpret_cast<f32x4*>(bp + (size_t)(d4 * 16) * BTOT + sb * 16) = acc[sb][d4];
}

// ---------------- combine stage A: slice-reduce chunks ----------------
__global__ __launch_bounds__(256)
void combineA(const float* __restrict__ pl, const float* __restrict__ pacc,
              float* __restrict__ part, int cper)
{
    int e = blockIdx.x * 256 + threadIdx.x;        // < ESPACE (66560)
    int s = blockIdx.y;
    int c0 = s * cper;
    float v0 = 0.f, v1 = 0.f;
    if (e < DD * BTOT) {                           // pacc element
        const float* p = pacc + (size_t)c0 * (DD * BTOT) + e;
#pragma unroll 2
        for (int i = 0; i + 1 < cper; i += 2) {
            v0 += p[(size_t)i * (DD * BTOT)];
            v1 += p[(size_t)(i + 1) * (DD * BTOT)];
        }
        if (cper & 1) v0 += p[(size_t)(cper - 1) * (DD * BTOT)];
    } else {                                       // pl element (wave-uniform branch)
        const float* p = pl + (size_t)c0 * BTOT + (e - DD * BTOT);
#pragma unroll 2
        for (int i = 0; i + 1 < cper; i += 2) {
            v0 += p[(size_t)i * BTOT];
            v1 += p[(size_t)(i + 1) * BTOT];
        }
        if (cper & 1) v0 += p[(size_t)(cper - 1) * BTOT];
    }
    part[(size_t)s * ESPACE + e] = v0 + v1;
}

// ---------------- combine stage B: sum 8 slices + divide ----------------
__global__ __launch_bounds__(256)
void combineB(const float* __restrict__ part, float* __restrict__ out)
{
    int t = blockIdx.x * 256 + threadIdx.x;        // < 65536
    int d = t >> 10, b = t & 1023;
    float v = 0.f, lssum = 0.f;
#pragma unroll
    for (int s = 0; s < NSLICE; ++s) {
        v     += part[(size_t)s * ESPACE + t];
        lssum += part[(size_t)s * ESPACE + DD * BTOT + b];
    }
    out[(size_t)b * DD + d] = v / lssum;
}

extern "C" void kernel_launch(void* const* d_in, const int* in_sizes, int n_in,
                              void* d_out, int out_size, void* d_ws, size_t ws_size,
                              hipStream_t stream)
{
    const float* q    = (const float*)d_in[0];
    const float* ctx  = (const float*)d_in[1];
    const float* K    = (const float*)d_in[2];
    const float* V    = (const float*)d_in[3];
    const float* CT   = (const float*)d_in[4];
    const float* TS   = (const float*)d_in[5];
    const int*   mask = (const int*)d_in[6];

    char* wsb = (char*)d_ws;
    u16* Qc = (u16*)(wsb);                                // 1024*96*2   = 196608
    u16* KC = (u16*)(wsb + 196608);                       // 65536*96*2  = 12582912
    u16* Vt = (u16*)(wsb + 196608 + 12582912);            // 64*65536*2  = 8388608
    size_t fixed = 196608 + 12582912 + 8388608;           // 21168128

    size_t chunk = (size_t)BTOT * (DD + 1) * sizeof(float);   // 266240
    size_t partB = (size_t)NSLICE * ESPACE * sizeof(float);   // 2129920
    int SPLIT = (int)((ws_size - fixed - partB) / chunk);
    if (SPLIT > 128) SPLIT = 128;                          // NB=512 = 2 blocks/CU
    SPLIT &= ~7;
    if (SPLIT < 8) SPLIT = 8;

    float* pl   = (float*)(wsb + fixed);                  // [SPLIT][1024]
    float* pacc = pl + (size_t)SPLIT * BTOT;              // [SPLIT][64][1024]
    float* part = pacc + (size_t)SPLIT * DD * BTOT;       // [8][66560]

    int mper = ((MTOT + SPLIT - 1) / SPLIT + 63) & ~63;   // multiple of 64
    int cper = SPLIT / NSLICE;

    prep_all<<<NROWBLK + NVTBLK, 256, 0, stream>>>(q, ctx, K, CT, TS, mask, V, Qc, KC, Vt);

    int NB = 4 * SPLIT;                                    // 4 row-tiles of 256
    epmem_mfma<<<NB, 256, 0, stream>>>(Qc, KC, Vt, pl, pacc, mper, NB);

    dim3 gA((ESPACE + 255) / 256, NSLICE);
    combineA<<<gA, 256, 0, stream>>>(pl, pacc, part, cper);
    combineB<<<(DD * BTOT) / 256, 256, 0, stream>>>(part, (float*)d_out);
}

// Round 14
// 55.549 us; speedup vs baseline: 1.9844x; 1.0084x over previous
//
#include <hip/hip_runtime.h>

typedef float f32x4 __attribute__((ext_vector_type(4)));
typedef __bf16 bf16x8 __attribute__((ext_vector_type(8)));
typedef unsigned int u32;
typedef unsigned short u16;

#define MTOT 65536
#define BTOT 1024
#define DD 64
#define LOG2E 1.44269504088896340736f
#define MFMA __builtin_amdgcn_mfma_f32_16x16x32_bf16

#define NROWBLK ((MTOT + BTOT) * 24 / 256)   // 6240
#define NVTBLK  (MTOT / 64)                  // 1024
#define ESPACE  (DD * BTOT + BTOT)           // 66560
#define NSLICE  8

__device__ __forceinline__ u16 f2bf(float f) { return __builtin_bit_cast(u16, (__bf16)f); }
__device__ __forceinline__ u32 pk2(float a, float b) {
    return (u32)f2bf(a) | ((u32)f2bf(b) << 16);
}
__device__ __forceinline__ bf16x8 ldg8(const u16* p) { return *reinterpret_cast<const bf16x8*>(p); }
__device__ __forceinline__ float fexp2(float x) {
#if __has_builtin(__builtin_amdgcn_exp2f)
    return __builtin_amdgcn_exp2f(x);   // single v_exp_f32, compiler-known (hazard-safe)
#else
    return exp2f(x);
#endif
}
__device__ __forceinline__ void glds16(const void* g, void* l) {
    __builtin_amdgcn_global_load_lds((const __attribute__((address_space(1))) u32*)g,
                                     (__attribute__((address_space(3))) u32*)l, 16, 0, 0);
}

// ---------------- fused precompute: Qc/KC rows + interleaved Vt (unchanged, proven) ----------------
__global__ __launch_bounds__(256)
void prep_all(const float* __restrict__ q, const float* __restrict__ ctx,
              const float* __restrict__ K, const float* __restrict__ CT,
              const float* __restrict__ TS, const int* __restrict__ mask,
              const float* __restrict__ V,
              u16* __restrict__ Qc, u16* __restrict__ KC, u16* __restrict__ Vt)
{
    __shared__ u16 L[64][68];
    const int blk = blockIdx.x, t = threadIdx.x;

    if (blk < NROWBLK) {
        const int R = MTOT + BTOT;
        int gid = blk * 256 + t;                   // R*24 total, exact
        float4 v = {0.f, 0.f, 0.f, 0.f};
        u16* dst;
        if (gid < R * 16) {                        // feature cols 0..63
            int row = gid >> 4, qd = gid & 15;
            bool isQ = row >= MTOT;
            int r2 = isQ ? row - MTOT : row;
            v = *reinterpret_cast<const float4*>((isQ ? q : K) + (size_t)r2 * 64 + qd * 4);
            if (isQ) { v.x *= LOG2E; v.y *= LOG2E; v.z *= LOG2E; v.w *= LOG2E; }
            dst = (isQ ? Qc : KC) + (size_t)r2 * 96 + qd * 4;
        } else if (gid < R * 20) {                 // context cols 64..79
            int i = gid - R * 16;
            int row = i >> 2, qd = i & 3;
            bool isQ = row >= MTOT;
            int r2 = isQ ? row - MTOT : row;
            v = *reinterpret_cast<const float4*>((isQ ? ctx : CT) + (size_t)r2 * 16 + qd * 4);
            if (isQ) { const float s = 0.5f * LOG2E; v.x *= s; v.y *= s; v.z *= s; v.w *= s; }
            dst = (isQ ? Qc : KC) + (size_t)r2 * 96 + 64 + qd * 4;
        } else {                                   // bias col 80 + pad 81..95
            int i = gid - R * 20;
            int row = i >> 2, qd = i & 3;
            bool isQ = row >= MTOT;
            int r2 = isQ ? row - MTOT : row;
            if (qd == 0)
                v.x = isQ ? LOG2E
                          : (mask[r2] ? 0.3f * __expf(-0.1f * (1000.0f - TS[r2])) : -100.0f);
            dst = (isQ ? Qc : KC) + (size_t)r2 * 96 + 80 + qd * 4;
        }
        ushort4 o = { f2bf(v.x), f2bf(v.y), f2bf(v.z), f2bf(v.w) };
        *reinterpret_cast<ushort4*>(dst) = o;
        return;
    }

    // ---- Vt part: interleaved transpose (pairs (x, 16+x)) ----
    const int m0 = (blk - NROWBLK) * 64;
#pragma unroll
    for (int p = 0; p < 4; ++p) {
        int fi = t + p * 256;              // float4 index 0..1023
        int mi = fi >> 4, di = (fi & 15) << 2;
        float4 v = *reinterpret_cast<const float4*>(V + (size_t)(m0 + mi) * 64 + di);
        ushort4 o = { f2bf(v.x), f2bf(v.y), f2bf(v.z), f2bf(v.w) };
        *reinterpret_cast<ushort4*>(&L[mi][di]) = o;
    }
    __syncthreads();
    const int d = t >> 2, seg = t & 3;
    u32 pk[8];
#pragma unroll
    for (int pr = 0; pr < 8; ++pr) {
        int c0 = seg * 16 + pr * 2;
        int g32 = c0 >> 5;
        int i0 = c0 & 31, i1 = (c0 + 1) & 31;
        int mp0 = g32 * 32 + (i0 >> 1) + (i0 & 1) * 16;   // interleave
        int mp1 = g32 * 32 + (i1 >> 1) + (i1 & 1) * 16;
        pk[pr] = (u32)L[mp0][d] | ((u32)L[mp1][d] << 16);
    }
    uint4 A = {pk[0], pk[1], pk[2], pk[3]}, B4 = {pk[4], pk[5], pk[6], pk[7]};
    u16* dst = Vt + (size_t)d * MTOT + m0 + seg * 16;
    *reinterpret_cast<uint4*>(dst)     = A;
    *reinterpret_cast<uint4*>(dst + 8) = B4;
}

// ---------------- main: 8 waves/block, 32 rows/wave, 4 waves/SIMD ----------------
__global__ __launch_bounds__(512, 4)
void epmem_mfma(const u16* __restrict__ Qc, const u16* __restrict__ KCg,
                const u16* __restrict__ Vtg,
                float* __restrict__ pl, float* __restrict__ pacc,
                int mper, int NB)
{
    __shared__ __align__(16) u16 KCs[2][64 * 96];    // 24 KB
    __shared__ __align__(16) u16 Vts[2][64 * 64];    // 16 KB
    __shared__ __align__(16) u16 Pb[8][32][40];      // 20 KB (per wave)

    const int tid = threadIdx.x;
    const int w = tid >> 6, lane = tid & 63;
    const int l15 = lane & 15, g = lane >> 4;

    const int bid = blockIdx.x;
    const int o = (bid & 7) * (NB >> 3) + (bid >> 3);     // XCD-bijective (NB % 8 == 0)
    const int rt = o & 3, ch = o >> 2;                    // 4 row-tiles of 256
    const int rbase = rt * 256 + w * 32;                  // wave owns 32 b-rows

    // Q fragments: 2 b-subtiles x 3 k-chunks (LOG2E pre-scaled)
    const u16* qp = Qc + (size_t)(rbase + l15) * 96 + g * 8;
    bf16x8 qf[2][3];
#pragma unroll
    for (int sb = 0; sb < 2; ++sb)
#pragma unroll
        for (int c = 0; c < 3; ++c)
            qf[sb][c] = ldg8(qp + sb * 16 * 96 + c * 32);

    const int m0 = ch * mper;
    const int m1 = (m0 + mper < MTOT) ? (m0 + mper) : MTOT;
    const int ntiles = (m1 > m0) ? ((m1 - m0) >> 6) : 0;

    // staging offsets (waves 0-3 only; inverse-swizzled global source, linear LDS dest)
    int kgo[3], vgo[2];
    if (w < 4) {
#pragma unroll
        for (int i = 0; i < 3; ++i) {
            int ol = w * 3072 + i * 1024 + lane * 16;
            int row = ol / 192;
            int c = (ol - row * 192) >> 4;                   // 0..11
            int u = (c < 8) ? (c ^ (row & 7)) : (8 + ((c & 3) ^ (row & 3)));
            kgo[i] = row * 192 + u * 16;
        }
#pragma unroll
        for (int i = 0; i < 2; ++i) {
            int ol = w * 2048 + i * 1024 + lane * 16;
            int row = ol >> 7, c = (ol >> 4) & 7;
            int u = c ^ (row & 7);
            vgo[i] = row * (MTOT * 2) + u * 16;
        }
    }

    // constant ones B-fragment (col 0 = 1.0)
    const u32 ow = (l15 == 0) ? 0x3F803F80u : 0u;
    const uint4 ou = {ow, ow, ow, ow};
    const bf16x8 onesf = __builtin_bit_cast(bf16x8, ou);

    f32x4 acc[2][4];
    f32x4 accl[2];
#pragma unroll
    for (int sb = 0; sb < 2; ++sb) {
        accl[sb] = (f32x4){0, 0, 0, 0};
#pragma unroll
        for (int d4 = 0; d4 < 4; ++d4) acc[sb][d4] = (f32x4){0, 0, 0, 0};
    }

    if (ntiles > 0 && w < 4) {
        const char* kb = (const char*)KCg + (size_t)m0 * 192;
        const char* vb = (const char*)Vtg + (size_t)m0 * 2;
#pragma unroll
        for (int i = 0; i < 3; ++i) glds16(kb + kgo[i], (char*)KCs[0] + w * 3072 + i * 1024);
#pragma unroll
        for (int i = 0; i < 2; ++i) glds16(vb + vgo[i], (char*)Vts[0] + w * 2048 + i * 1024);
    }
    __syncthreads();

    char* pbw = (char*)Pb[w];
    const int xr = l15 & 7;
    const int x3 = l15 & 3;

    int cur = 0;
    for (int t = 0; t < ntiles; ++t) {
        if (t + 1 < ntiles && w < 4) {
            int mt = m0 + ((t + 1) << 6);
            const char* kb = (const char*)KCg + (size_t)mt * 192;
            const char* vb = (const char*)Vtg + (size_t)mt * 2;
            int nb = cur ^ 1;
#pragma unroll
            for (int i = 0; i < 3; ++i) glds16(kb + kgo[i], (char*)KCs[nb] + w * 3072 + i * 1024);
#pragma unroll
            for (int i = 0; i < 2; ++i) glds16(vb + vgo[i], (char*)Vts[nb] + w * 2048 + i * 1024);
        }
        const char* kcb = (const char*)KCs[cur];
        const char* vtb = (const char*)Vts[cur];

#pragma unroll
        for (int j = 0; j < 2; ++j) {               // two 32-m steps per 64-m tile
            bf16x8 kf[2][3];
#pragma unroll
            for (int s = 0; s < 2; ++s) {
                int row = j * 32 + s * 16 + l15;
                kf[s][0] = *reinterpret_cast<const bf16x8*>(kcb + row * 192 + (((0 + g) ^ xr) << 4));
                kf[s][1] = *reinterpret_cast<const bf16x8*>(kcb + row * 192 + (((4 + g) ^ xr) << 4));
                kf[s][2] = *reinterpret_cast<const bf16x8*>(kcb + row * 192 + ((8 + (g ^ x3)) << 4));
            }
            bf16x8 vf[4];
#pragma unroll
            for (int d4 = 0; d4 < 4; ++d4) {
                int row = d4 * 16 + l15;
                vf[d4] = *reinterpret_cast<const bf16x8*>(vtb + row * 128 + (((j * 4 + g) ^ xr) << 4));
            }

            f32x4 S00 = {0,0,0,0}, S01 = {0,0,0,0}, S10 = {0,0,0,0}, S11 = {0,0,0,0};
            S00 = MFMA(qf[0][0], kf[0][0], S00,0,0,0); S00 = MFMA(qf[0][1], kf[0][1], S00,0,0,0); S00 = MFMA(qf[0][2], kf[0][2], S00,0,0,0);
            S01 = MFMA(qf[0][0], kf[1][0], S01,0,0,0); S01 = MFMA(qf[0][1], kf[1][1], S01,0,0,0); S01 = MFMA(qf[0][2], kf[1][2], S01,0,0,0);
            S10 = MFMA(qf[1][0], kf[0][0], S10,0,0,0); S10 = MFMA(qf[1][1], kf[0][1], S10,0,0,0); S10 = MFMA(qf[1][2], kf[0][2], S10,0,0,0);
            S11 = MFMA(qf[1][0], kf[1][0], S11,0,0,0); S11 = MFMA(qf[1][1], kf[1][1], S11,0,0,0); S11 = MFMA(qf[1][2], kf[1][2], S11,0,0,0);

#pragma unroll
            for (int r = 0; r < 4; ++r) {
                float p00 = fexp2(S00[r]), p01 = fexp2(S01[r]);
                float p10 = fexp2(S10[r]), p11 = fexp2(S11[r]);
                int row0 = g * 4 + r, row1 = 16 + g * 4 + r;
                int cw = (((l15 >> 2) ^ r) << 4) | ((l15 & 3) << 2);
                *(u32*)(pbw + row0 * 80 + cw) = pk2(p00, p01);   // pair (m'=l15, 16+l15)
                *(u32*)(pbw + row1 * 80 + cw) = pk2(p10, p11);
            }
            bf16x8 pa0 = *reinterpret_cast<const bf16x8*>(pbw + l15 * 80        + ((g ^ x3) << 4));
            bf16x8 pa1 = *reinterpret_cast<const bf16x8*>(pbw + (16 + l15) * 80 + ((g ^ x3) << 4));

            acc[0][0] = MFMA(pa0, vf[0], acc[0][0],0,0,0); acc[0][1] = MFMA(pa0, vf[1], acc[0][1],0,0,0);
            acc[0][2] = MFMA(pa0, vf[2], acc[0][2],0,0,0); acc[0][3] = MFMA(pa0, vf[3], acc[0][3],0,0,0);
            acc[1][0] = MFMA(pa1, vf[0], acc[1][0],0,0,0); acc[1][1] = MFMA(pa1, vf[1], acc[1][1],0,0,0);
            acc[1][2] = MFMA(pa1, vf[2], acc[1][2],0,0,0); acc[1][3] = MFMA(pa1, vf[3], acc[1][3],0,0,0);
            accl[0] = MFMA(pa0, onesf, accl[0],0,0,0);     // lsum of quantized P
            accl[1] = MFMA(pa1, onesf, accl[1],0,0,0);
        }
        __syncthreads();
        cur ^= 1;
    }

    // pl[ch][b]: lsum in col 0 of accl (lanes l15==0), rows b = rbase + sb*16 + g*4 + r
    if (l15 == 0) {
#pragma unroll
        for (int sb = 0; sb < 2; ++sb)
            *reinterpret_cast<f32x4*>(pl + (size_t)ch * BTOT + rbase + sb * 16 + g * 4) = accl[sb];
    }

    // pacc[ch][d][b]: lane col d = d4*16+l15; rows b = rbase + sb*16 + g*4 + r
    float* bp = pacc + ((size_t)ch * DD + l15) * BTOT + rbase + g * 4;
#pragma unroll
    for (int sb = 0; sb < 2; ++sb)
#pragma unroll
        for (int d4 = 0; d4 < 4; ++d4)
            *reinterpret_cast<f32x4*>(bp + (size_t)(d4 * 16) * BTOT + sb * 16) = acc[sb][d4];
}

// ---------------- combine stage A: slice-reduce chunks ----------------
__global__ __launch_bounds__(256)
void combineA(const float* __restrict__ pl, const float* __restrict__ pacc,
              float* __restrict__ part, int cper)
{
    int e = blockIdx.x * 256 + threadIdx.x;        // < ESPACE (66560)
    int s = blockIdx.y;
    int c0 = s * cper;
    float v0 = 0.f, v1 = 0.f;
    if (e < DD * BTOT) {                           // pacc element
        const float* p = pacc + (size_t)c0 * (DD * BTOT) + e;
#pragma unroll 2
        for (int i = 0; i + 1 < cper; i += 2) {
            v0 += p[(size_t)i * (DD * BTOT)];
            v1 += p[(size_t)(i + 1) * (DD * BTOT)];
        }
        if (cper & 1) v0 += p[(size_t)(cper - 1) * (DD * BTOT)];
    } else {                                       // pl element (wave-uniform branch)
        const float* p = pl + (size_t)c0 * BTOT + (e - DD * BTOT);
#pragma unroll 2
        for (int i = 0; i + 1 < cper; i += 2) {
            v0 += p[(size_t)i * BTOT];
            v1 += p[(size_t)(i + 1) * BTOT];
        }
        if (cper & 1) v0 += p[(size_t)(cper - 1) * BTOT];
    }
    part[(size_t)s * ESPACE + e] = v0 + v1;
}

// ---------------- combine stage B: sum 8 slices + divide ----------------
__global__ __launch_bounds__(256)
void combineB(const float* __restrict__ part, float* __restrict__ out)
{
    int t = blockIdx.x * 256 + threadIdx.x;        // < 65536
    int d = t >> 10, b = t & 1023;
    float v = 0.f, lssum = 0.f;
#pragma unroll
    for (int s = 0; s < NSLICE; ++s) {
        v     += part[(size_t)s * ESPACE + t];
        lssum += part[(size_t)s * ESPACE + DD * BTOT + b];
    }
    out[(size_t)b * DD + d] = v / lssum;
}

extern "C" void kernel_launch(void* const* d_in, const int* in_sizes, int n_in,
                              void* d_out, int out_size, void* d_ws, size_t ws_size,
                              hipStream_t stream)
{
    const float* q    = (const float*)d_in[0];
    const float* ctx  = (const float*)d_in[1];
    const float* K    = (const float*)d_in[2];
    const float* V    = (const float*)d_in[3];
    const float* CT   = (const float*)d_in[4];
    const float* TS   = (const float*)d_in[5];
    const int*   mask = (const int*)d_in[6];

    char* wsb = (char*)d_ws;
    u16* Qc = (u16*)(wsb);                                // 1024*96*2   = 196608
    u16* KC = (u16*)(wsb + 196608);                       // 65536*96*2  = 12582912
    u16* Vt = (u16*)(wsb + 196608 + 12582912);            // 64*65536*2  = 8388608
    size_t fixed = 196608 + 12582912 + 8388608;           // 21168128

    size_t chunk = (size_t)BTOT * (DD + 1) * sizeof(float);   // 266240
    size_t partB = (size_t)NSLICE * ESPACE * sizeof(float);   // 2129920
    int SPLIT = (int)((ws_size - fixed - partB) / chunk);
    if (SPLIT > 128) SPLIT = 128;                          // NB=512 = 2 blocks/CU
    SPLIT &= ~7;
    if (SPLIT < 8) SPLIT = 8;

    float* pl   = (float*)(wsb + fixed);                  // [SPLIT][1024]
    float* pacc = pl + (size_t)SPLIT * BTOT;              // [SPLIT][64][1024]
    float* part = pacc + (size_t)SPLIT * DD * BTOT;       // [8][66560]

    int mper = ((MTOT + SPLIT - 1) / SPLIT + 63) & ~63;   // multiple of 64
    int cper = SPLIT / NSLICE;

    prep_all<<<NROWBLK + NVTBLK, 256, 0, stream>>>(q, ctx, K, CT, TS, mask, V, Qc, KC, Vt);

    int NB = 4 * SPLIT;                                    // 4 row-tiles of 256 rows
    epmem_mfma<<<NB, 512, 0, stream>>>(Qc, KC, Vt, pl, pacc, mper, NB);

    dim3 gA((ESPACE + 255) / 256, NSLICE);
    combineA<<<gA, 256, 0, stream>>>(pl, pacc, part, cper);
    combineB<<<(DD * BTOT) / 256, 256, 0, stream>>>(part, (float*)d_out);
}